// Round 6
// baseline (138.525 us; speedup 1.0000x reference)
//
#include <hip/hip_runtime.h>
#include <hip/hip_bf16.h>

// MessagePassing: out[dst[e], :] += x[src[e], :] * w[e]
// x: [N, 64] f32, edge_index: [2, E] int32 (row0=src, row1=dst), w: [E,1] f32
// out: [N, 64] f32
//
// Round-6: gather uses float4 lanes (16 lanes = one 256B x-row), wave = 4
// edge-rows per step, 2x unroll -> 8 rows (32 dwordx4) in flight per wave.
// Cross-subrow reduce via shfl_xor. Partition unchanged from round-5.

constexpr int D_FEAT        = 64;
constexpr int BIN_SHIFT     = 7;                  // 128 nodes / bin
constexpr int NODES_PER_BIN = 1 << BIN_SHIFT;
constexpr int NBINS_MAX     = 1024;               // supports n_nodes <= 131072
constexpr int BIN_CAP       = 2048;               // mean 1536 at E/N=12 -> +13 sigma
constexpr int EPB           = 4096;               // edges per partition block
constexpr int OVF_CAP       = 32768;

__device__ __forceinline__ int wave_incl_scan(int v, int lane) {
    #pragma unroll
    for (int d = 1; d < 64; d <<= 1) {
        int t = __shfl_up(v, d);
        if (lane >= d) v += t;
    }
    return v;
}

// ---------------- K1: partition edges into coarse bins (1024 thr) ----------------
__global__ __launch_bounds__(1024) void mp_partition(
    const int* __restrict__ src, const int* __restrict__ dst,
    const float* __restrict__ w,
    int*  __restrict__ gcnt,       // [nbins] global per-bin cursors (pre-zeroed)
    int2* __restrict__ payload,    // [nbins * BIN_CAP]
    int*  __restrict__ ovf_cnt, int4* __restrict__ ovf,
    int n_edges, int nbins)
{
    __shared__ int cnt[NBINS_MAX];
    __shared__ int start[NBINS_MAX];
    __shared__ int cur[NBINS_MAX];
    __shared__ int gbase[NBINS_MAX];
    __shared__ unsigned short binof[EPB];
    __shared__ int2 sorted[EPB];
    __shared__ int wsum[16];

    const int t    = threadIdx.x;
    const int lane = t & 63;
    const int wid  = t >> 6;
    const int base = blockIdx.x * EPB;
    const int nblk = min(EPB, n_edges - base);

    if (t < NBINS_MAX) cnt[t] = 0;
    __syncthreads();

    // count pass (dst only), one int4 per thread
    const int i4 = (base >> 2) + t;
    int4 d4 = make_int4(0, 0, 0, 0);
    bool have = (i4 * 4 < n_edges);
    if (have) {
        d4 = reinterpret_cast<const int4*>(dst)[i4];
        atomicAdd(&cnt[d4.x >> BIN_SHIFT], 1);
        atomicAdd(&cnt[d4.y >> BIN_SHIFT], 1);
        atomicAdd(&cnt[d4.z >> BIN_SHIFT], 1);
        atomicAdd(&cnt[d4.w >> BIN_SHIFT], 1);
    }
    __syncthreads();

    // block exclusive scan over nbins (1 bin / thread, nbins <= 1024)
    const int c = (t < nbins) ? cnt[t] : 0;
    const int incl = wave_incl_scan(c, lane);
    if (lane == 63) wsum[wid] = incl;
    __syncthreads();
    int woff = 0;
    #pragma unroll
    for (int k = 0; k < 16; ++k) woff += (k < wid) ? wsum[k] : 0;
    const int excl = woff + incl - c;
    if (t < nbins) {
        start[t] = excl;
        cur[t]   = excl;
        if (c > 0) gbase[t] = atomicAdd(&gcnt[t], c);
    }
    __syncthreads();

    // scatter into LDS sorted-by-bin order
    if (have) {
        const int4   s4 = reinterpret_cast<const int4*>(src)[i4];
        const float4 w4 = reinterpret_cast<const float4*>(w)[i4];
        const int   dd[4] = {d4.x, d4.y, d4.z, d4.w};
        const int   ss[4] = {s4.x, s4.y, s4.z, s4.w};
        const float ww[4] = {w4.x, w4.y, w4.z, w4.w};
        #pragma unroll
        for (int j = 0; j < 4; ++j) {
            const int b   = dd[j] >> BIN_SHIFT;
            const int low = dd[j] & (NODES_PER_BIN - 1);
            const int p   = atomicAdd(&cur[b], 1);
            sorted[p] = make_int2((low << 20) | ss[j], __float_as_int(ww[j]));
            binof[p]  = (unsigned short)b;
        }
    }
    __syncthreads();

    // coalesced flush: consecutive LDS slots -> consecutive global slots per run
    #pragma unroll
    for (int k = 0; k < EPB / 1024; ++k) {
        const int i = k * 1024 + t;
        if (i >= nblk) break;
        const int b    = binof[i];
        const int idx  = i - start[b];
        const int gpos = gbase[b] + idx;
        const int2 e   = sorted[i];
        if (gpos < BIN_CAP) {
            payload[(size_t)b * BIN_CAP + gpos] = e;
        } else {
            const int op = atomicAdd(ovf_cnt, 1);
            if (op < OVF_CAP)
                ovf[op] = make_int4((b << BIN_SHIFT) + (e.x >> 20),
                                    e.x & 0xFFFFF, e.y, 0);
        }
    }
}

// ---------------- K2: per-bin fine sort (LDS) + float4 gather ----------------
__global__ __launch_bounds__(512) void mp_bin_gather(
    const float* __restrict__ x,
    const int*  __restrict__ gcnt,
    const int2* __restrict__ payload,
    const int*  __restrict__ ovf_cnt, const int4* __restrict__ ovf,
    float* __restrict__ out, int n_nodes)
{
    __shared__ int2 sraw[BIN_CAP];                  // 16 KB (global staged once)
    __shared__ int2 sedge[BIN_CAP];                 // 16 KB (node-sorted)
    __shared__ int ncnt[NODES_PER_BIN];
    __shared__ int nstart[NODES_PER_BIN + 1];
    __shared__ int ncur[NODES_PER_BIN];

    const int b    = blockIdx.x;
    const int t    = threadIdx.x;
    const int lane = t & 63;
    const int wid  = t >> 6;
    const int sub  = lane >> 4;          // 0..3: edge sub-row
    const int fl   = (lane & 15) * 4;    // float4 feature base

    const int m = min(gcnt[b], BIN_CAP);
    const int2* pl = payload + (size_t)b * BIN_CAP;

    for (int i = t; i < NODES_PER_BIN; i += 512) ncnt[i] = 0;
    __syncthreads();

    // stage payload into LDS once + histogram by node
    for (int i = t; i < m; i += 512) {
        const int2 e = pl[i];
        sraw[i] = e;
        atomicAdd(&ncnt[e.x >> 20], 1);
    }
    __syncthreads();

    // exclusive prefix over 128 node counters (wave 0)
    if (t < 64) {
        const int a0 = ncnt[t], a1 = ncnt[64 + t];
        const int s0 = wave_incl_scan(a0, t);
        const int s1 = wave_incl_scan(a1, t);
        const int tot0 = __shfl(s0, 63);
        nstart[t]      = s0 - a0;
        nstart[64 + t] = tot0 + s1 - a1;
        if (t == 63) nstart[128] = tot0 + s1;
    }
    __syncthreads();
    for (int i = t; i < NODES_PER_BIN; i += 512) ncur[i] = nstart[i];
    __syncthreads();

    // LDS -> LDS node-sorted scatter
    for (int i = t; i < m; i += 512) {
        const int2 e = sraw[i];
        const int p  = atomicAdd(&ncur[e.x >> 20], 1);
        sedge[p] = e;
    }
    __syncthreads();

    const int novf = *ovf_cnt;  // usually 0

    // gather: wave per node; 4 edges/step (16 lanes per edge-row), 2x unroll
    for (int n = wid; n < NODES_PER_BIN; n += 8) {
        const int node = (b << BIN_SHIFT) + n;
        if (node >= n_nodes) break;
        const int s0 = nstart[n], s1 = nstart[n + 1];

        float4 aA = make_float4(0.f, 0.f, 0.f, 0.f);
        float4 aB = make_float4(0.f, 0.f, 0.f, 0.f);

        int base = s0;
        for (; base + 8 <= s1; base += 8) {
            const int2 pA = sedge[base + sub];
            const int2 pB = sedge[base + 4 + sub];
            const float4 xA = *reinterpret_cast<const float4*>(
                x + (size_t)(pA.x & 0xFFFFF) * D_FEAT + fl);
            const float4 xB = *reinterpret_cast<const float4*>(
                x + (size_t)(pB.x & 0xFFFFF) * D_FEAT + fl);
            const float wA = __int_as_float(pA.y);
            const float wB = __int_as_float(pB.y);
            aA.x = fmaf(xA.x, wA, aA.x); aA.y = fmaf(xA.y, wA, aA.y);
            aA.z = fmaf(xA.z, wA, aA.z); aA.w = fmaf(xA.w, wA, aA.w);
            aB.x = fmaf(xB.x, wB, aB.x); aB.y = fmaf(xB.y, wB, aB.y);
            aB.z = fmaf(xB.z, wB, aB.z); aB.w = fmaf(xB.w, wB, aB.w);
        }
        if (base + 4 <= s1) {
            const int2 p = sedge[base + sub];
            const float4 xv = *reinterpret_cast<const float4*>(
                x + (size_t)(p.x & 0xFFFFF) * D_FEAT + fl);
            const float ww = __int_as_float(p.y);
            aA.x = fmaf(xv.x, ww, aA.x); aA.y = fmaf(xv.y, ww, aA.y);
            aA.z = fmaf(xv.z, ww, aA.z); aA.w = fmaf(xv.w, ww, aA.w);
            base += 4;
        }
        const int rem = s1 - base;      // 0..3
        if (sub < rem) {
            const int2 p = sedge[base + sub];
            const float4 xv = *reinterpret_cast<const float4*>(
                x + (size_t)(p.x & 0xFFFFF) * D_FEAT + fl);
            const float ww = __int_as_float(p.y);
            aB.x = fmaf(xv.x, ww, aB.x); aB.y = fmaf(xv.y, ww, aB.y);
            aB.z = fmaf(xv.z, ww, aB.z); aB.w = fmaf(xv.w, ww, aB.w);
        }

        float4 r = make_float4(aA.x + aB.x, aA.y + aB.y, aA.z + aB.z, aA.w + aB.w);
        // reduce across the 4 sub-rows (xor 16, then xor 32)
        r.x += __shfl_xor(r.x, 16); r.y += __shfl_xor(r.y, 16);
        r.z += __shfl_xor(r.z, 16); r.w += __shfl_xor(r.w, 16);
        r.x += __shfl_xor(r.x, 32); r.y += __shfl_xor(r.y, 32);
        r.z += __shfl_xor(r.z, 32); r.w += __shfl_xor(r.w, 32);

        if (novf > 0) {  // rare overflow path
            const int lim = min(novf, OVF_CAP);
            for (int j = 0; j < lim; ++j) {
                const int4 o = ovf[j];
                if (o.x == node) {
                    const float4 xv = *reinterpret_cast<const float4*>(
                        x + (size_t)o.y * D_FEAT + fl);
                    const float ww = __int_as_float(o.z);
                    r.x = fmaf(xv.x, ww, r.x); r.y = fmaf(xv.y, ww, r.y);
                    r.z = fmaf(xv.z, ww, r.z); r.w = fmaf(xv.w, ww, r.w);
                }
            }
        }
        if (sub == 0)
            *reinterpret_cast<float4*>(out + (size_t)node * D_FEAT + fl) = r;
    }
}

// ---------------- fallback: atomic scatter (round-1, known correct) ----------------
__global__ __launch_bounds__(256) void mp_scatter_atomic(
    const float* __restrict__ x, const int* __restrict__ src,
    const int* __restrict__ dst, const float* __restrict__ w,
    float* __restrict__ out, int n_edges)
{
    const int gtid = blockIdx.x * blockDim.x + threadIdx.x;
    const int edge = gtid >> 6;
    const int lane = threadIdx.x & 63;
    if (edge >= n_edges) return;
    const int s = src[edge];
    const int d = dst[edge];
    const float ww = w[edge];
    atomicAdd(&out[(size_t)d * D_FEAT + lane], x[(size_t)s * D_FEAT + lane] * ww);
}

extern "C" void kernel_launch(void* const* d_in, const int* in_sizes, int n_in,
                              void* d_out, int out_size, void* d_ws, size_t ws_size,
                              hipStream_t stream)
{
    const float* x          = (const float*)d_in[0];
    const int*   edge_index = (const int*)d_in[1];   // [2, E]
    const float* w          = (const float*)d_in[2]; // [E, 1]
    float*       out        = (float*)d_out;

    const int n_edges = in_sizes[1] / 2;
    const int n_nodes = in_sizes[0] / D_FEAT;
    const int* src = edge_index;
    const int* dst = edge_index + n_edges;

    const int nbins = (n_nodes + NODES_PER_BIN - 1) >> BIN_SHIFT;

    // ws layout: gcnt[NBINS_MAX] | ovf_cnt(+pad to 64 ints) | ovf[OVF_CAP] int4 | payload[nbins*BIN_CAP] int2
    int*  gcnt    = (int*)d_ws;
    int*  ovf_cnt = gcnt + NBINS_MAX;
    int4* ovf     = (int4*)(gcnt + NBINS_MAX + 64);
    int2* payload = (int2*)(ovf + OVF_CAP);
    const size_t need = (size_t)(NBINS_MAX + 64) * 4 + (size_t)OVF_CAP * 16
                      + (size_t)nbins * BIN_CAP * 8;

    const bool ok = (ws_size >= need) && (nbins <= NBINS_MAX) && ((n_edges & 3) == 0);

    if (ok) {
        hipMemsetAsync(gcnt, 0, (size_t)(NBINS_MAX + 64) * 4, stream);
        const int g1 = (n_edges + EPB - 1) / EPB;
        mp_partition<<<g1, 1024, 0, stream>>>(src, dst, w, gcnt, payload,
                                              ovf_cnt, ovf, n_edges, nbins);
        mp_bin_gather<<<nbins, 512, 0, stream>>>(x, gcnt, payload,
                                                 ovf_cnt, ovf, out, n_nodes);
        return;
    }

    // fallback: atomic scatter
    hipMemsetAsync(d_out, 0, (size_t)out_size * sizeof(float), stream);
    const int grid = (int)(((size_t)n_edges * 64 + 255) / 256);
    mp_scatter_atomic<<<grid, 256, 0, stream>>>(x, src, dst, w, out, n_edges);
}